// Round 5
// baseline (409.626 us; speedup 1.0000x reference)
//
#include <hip/hip_runtime.h>
#include <hip/hip_bf16.h>
#include <math.h>

#define S_LEN 2048
#define NHEAD 16
#define DMODEL 1024

typedef short bf16x8 __attribute__((ext_vector_type(8)));
typedef float f32x4 __attribute__((ext_vector_type(4)));

static __device__ __forceinline__ unsigned short bfbits(float x) {
    __hip_bfloat16 h = __float2bfloat16(x);   // round-to-nearest
    unsigned short u; __builtin_memcpy(&u, &h, 2); return u;
}
static __device__ __forceinline__ float bf2f(unsigned short u) {
    union { unsigned int i; float f; } v; v.i = ((unsigned int)u) << 16; return v.f;
}
// round-to-nearest split: x ~= hi + lo, rel err ~2^-18
static __device__ __forceinline__ void splitRN(float x, unsigned short& hi, unsigned short& lo) {
    unsigned short h = bfbits(x);
    float r = x - bf2f(h);
    hi = h; lo = bfbits(r);
}
static __device__ __forceinline__ void split4(float4 x, ushort4& h4, ushort4& l4) {
    unsigned short h0,l0,h1,l1,h2,l2,h3,l3;
    splitRN(x.x,h0,l0); splitRN(x.y,h1,l1); splitRN(x.z,h2,l2); splitRN(x.w,h3,l3);
    h4 = make_ushort4(h0,h1,h2,h3); l4 = make_ushort4(l0,l1,l2,l3);
}

__device__ __forceinline__ int mask_at(const void* mp, int enc, int s) {
    if (enc) return ((const unsigned char*)mp)[s] != 0;
    return ((const unsigned int*)mp)[s] != 0u;
}

__global__ void detect_kernel(const void* __restrict__ mask, int* __restrict__ flags) {
    if (threadIdx.x == 0 && blockIdx.x == 0) {
        const unsigned int* m = (const unsigned int*)mask;
        int bytey = 0;
        for (int i = 0; i < 8; ++i) {
            unsigned int u = m[i];
            if (u != 0u && u != 1u && u != 0x3F800000u) bytey = 1;
        }
        flags[0] = bytey;
    }
}

// Pre-split + pre-layout W in MFMA-fragment order:
// Wh/Wl[stream][h][dt][kc][lane][8]; a wave's per-chunk fragment load is ONE
// coalesced 1 KB read.
__global__ __launch_bounds__(256)
void presplit_w(const float* __restrict__ ll, const float* __restrict__ bproj,
                unsigned short* __restrict__ Wh, unsigned short* __restrict__ Wl) {
    __shared__ unsigned short Th[64][72], Tl[64][72];   // [n][d_local]
    const int t = threadIdx.x;
    const int bid = blockIdx.x;
    const int stream = bid >> 8;
    const int rem = bid & 255;
    const int h = rem >> 4;
    const int d0 = (rem & 15) << 6;
    const float* src = (stream == 3) ? bproj : (ll + (size_t)stream * 1048576);
#pragma unroll
    for (int rep = 0; rep < 4; ++rep) {
        int fid = rep * 256 + t;
        int dl = fid >> 4, n4 = (fid & 15) * 4;
        float4 w = *(const float4*)&src[(size_t)(d0 + dl) * 1024 + h * 64 + n4];
        unsigned short hh, lo2;
#pragma unroll
        for (int m = 0; m < 4; ++m) { splitRN((&w.x)[m], hh, lo2); Th[n4+m][dl] = hh; Tl[n4+m][dl] = lo2; }
    }
    __syncthreads();
    size_t obase = (size_t)stream * 1048576;
#pragma unroll
    for (int rep = 0; rep < 2; ++rep) {
        int wid = rep * 256 + t;
        int n = wid >> 3, dl8 = (wid & 7) * 8;
        int dtile = n >> 4, cc = n & 15;
        int dglob = d0 + dl8;
        int kc = dglob >> 5;
        int qd = (dglob >> 3) & 3;
        size_t off = obase + (size_t)(h * 4 + dtile) * 16384 + (size_t)kc * 512
                   + (size_t)(qd * 16 + cc) * 8;
        *(uint4*)&Wh[off] = *(uint4*)&Th[n][dl8];
        *(uint4*)&Wl[off] = *(uint4*)&Tl[n][dl8];
    }
}

// Fused q/k/v/b_rotate projection v6: double-buffered X LDS -> ONE barrier per
// chunk (was 2); staging writes to buf^1 overlap MFMAs on buf; X prefetch 2
// chunks ahead. LDS 35840 B, 4 blocks/CU.
__global__ __launch_bounds__(256, 4)
void proj_fused6(const float* __restrict__ Xq, const float* __restrict__ Xk,
                 const float* __restrict__ Xv, const float* __restrict__ Xb,
                 const unsigned short* __restrict__ Wh, const unsigned short* __restrict__ Wl,
                 unsigned short* __restrict__ qhi, unsigned short* __restrict__ qlo,
                 unsigned short* __restrict__ khi, unsigned short* __restrict__ klo,
                 unsigned short* __restrict__ vhi) {
    __shared__ unsigned short smem[17920];   // 2 bufs x 7 arrays x [32][40] ushort
    // epilogue reuse windows:
    unsigned short (*T0)[72] = (unsigned short(*)[72])(smem + 0);
    unsigned short (*T1)[72] = (unsigned short(*)[72])(smem + 2304);
    unsigned short (*T2)[40] = (unsigned short(*)[40])(smem + 4608);

    const int t = threadIdx.x;
    // swizzle: xcd = lin&7 (round-robin dispatch); within an XCD, 8 consecutive
    // blocks share h (W L2 reuse); s-ranges are XCD-exclusive (X L2 locality).
    const int lin = blockIdx.x;
    const int xcd = lin & 7;
    const int inner = lin >> 3;          // 0..127
    const int h = inner >> 3;            // 0..15
    const int sg = inner & 7;            // 0..7
    const int s0 = (xcd * 8 + sg) * 32;
    const int lane = t & 63, dt = t >> 6, quad = lane >> 4, c = lane & 15;

    f32x4 aq[2], ak[2], av[2], ab[2];
#pragma unroll
    for (int i = 0; i < 2; ++i) {
        aq[i] = (f32x4){0.f,0.f,0.f,0.f}; ak[i] = (f32x4){0.f,0.f,0.f,0.f};
        av[i] = (f32x4){0.f,0.f,0.f,0.f}; ab[i] = (f32x4){0.f,0.f,0.f,0.f};
    }

    const int xr = t >> 3, xc = (t & 7) * 4;
    const size_t xg = (size_t)(s0 + xr) * DMODEL + xc;
    const size_t wb = (size_t)(h * 4 + dt) * 16384 + (size_t)lane * 8;

#define XARR(name, b, i) unsigned short (*name)[40] = (unsigned short(*)[40])(smem + (b) * 8960 + (i) * 1280)

    float4 pq, pk, pv, pb;
    // chunk 0 -> regs -> LDS buf0
    pq = *(const float4*)&Xq[xg];
    pk = *(const float4*)&Xk[xg];
    pv = *(const float4*)&Xv[xg];
    pb = *(const float4*)&Xb[xg];
    {
        XARR(XQh,0,0); XARR(XQl,0,1); XARR(XKh,0,2); XARR(XKl,0,3);
        XARR(XVh,0,4); XARR(XBh,0,5); XARR(XBl,0,6);
        ushort4 h4, l4;
        split4(pq, h4, l4); *(ushort4*)&XQh[xr][xc] = h4; *(ushort4*)&XQl[xr][xc] = l4;
        split4(pk, h4, l4); *(ushort4*)&XKh[xr][xc] = h4; *(ushort4*)&XKl[xr][xc] = l4;
        split4(pb, h4, l4); *(ushort4*)&XBh[xr][xc] = h4; *(ushort4*)&XBl[xr][xc] = l4;
        *(ushort4*)&XVh[xr][xc] = make_ushort4(bfbits(pv.x),bfbits(pv.y),bfbits(pv.z),bfbits(pv.w));
    }
    // chunk 1 -> regs
    pq = *(const float4*)&Xq[xg + 32];
    pk = *(const float4*)&Xk[xg + 32];
    pv = *(const float4*)&Xv[xg + 32];
    pb = *(const float4*)&Xb[xg + 32];
    __syncthreads();

    for (int kc = 0; kc < 32; ++kc) {
        const int cb = kc & 1, nb = cb ^ 1;
        // W fragments for this chunk (L2-hot: 8 same-XCD blocks share the region)
        size_t wo = wb + (size_t)kc * 512;
        bf16x8 aQh = *(const bf16x8*)&Wh[wo];
        bf16x8 aQl = *(const bf16x8*)&Wl[wo];
        bf16x8 aKh = *(const bf16x8*)&Wh[1048576 + wo];
        bf16x8 aKl = *(const bf16x8*)&Wl[1048576 + wo];
        bf16x8 aVh = *(const bf16x8*)&Wh[2097152 + wo];
        bf16x8 aVl = *(const bf16x8*)&Wl[2097152 + wo];
        bf16x8 aBh = *(const bf16x8*)&Wh[3145728 + wo];
        bf16x8 aBl = *(const bf16x8*)&Wl[3145728 + wo];

        // stage chunk kc+1 (in px) into the other buffer — overlaps MFMAs below
        if (kc + 1 < 32) {
            XARR(XQh,nb,0); XARR(XQl,nb,1); XARR(XKh,nb,2); XARR(XKl,nb,3);
            XARR(XVh,nb,4); XARR(XBh,nb,5); XARR(XBl,nb,6);
            ushort4 h4, l4;
            split4(pq, h4, l4); *(ushort4*)&XQh[xr][xc] = h4; *(ushort4*)&XQl[xr][xc] = l4;
            split4(pk, h4, l4); *(ushort4*)&XKh[xr][xc] = h4; *(ushort4*)&XKl[xr][xc] = l4;
            split4(pb, h4, l4); *(ushort4*)&XBh[xr][xc] = h4; *(ushort4*)&XBl[xr][xc] = l4;
            *(ushort4*)&XVh[xr][xc] = make_ushort4(bfbits(pv.x),bfbits(pv.y),bfbits(pv.z),bfbits(pv.w));
        }
        // prefetch chunk kc+2 -> regs (in flight across this chunk's MFMAs)
        if (kc + 2 < 32) {
            size_t g = xg + (size_t)(kc + 2) * 32;
            pq = *(const float4*)&Xq[g];
            pk = *(const float4*)&Xk[g];
            pv = *(const float4*)&Xv[g];
            pb = *(const float4*)&Xb[g];
        }

        {
            XARR(XQh,cb,0); XARR(XQl,cb,1); XARR(XKh,cb,2); XARR(XKl,cb,3);
            XARR(XVh,cb,4); XARR(XBh,cb,5); XARR(XBl,cb,6);
#pragma unroll
            for (int st = 0; st < 2; ++st) {
                bf16x8 b1 = *(bf16x8*)&XQh[st*16+c][quad*8];
                bf16x8 b2 = *(bf16x8*)&XQl[st*16+c][quad*8];
                aq[st] = __builtin_amdgcn_mfma_f32_16x16x32_bf16(aQh, b1, aq[st], 0, 0, 0);
                aq[st] = __builtin_amdgcn_mfma_f32_16x16x32_bf16(aQh, b2, aq[st], 0, 0, 0);
                aq[st] = __builtin_amdgcn_mfma_f32_16x16x32_bf16(aQl, b1, aq[st], 0, 0, 0);
                aq[st] = __builtin_amdgcn_mfma_f32_16x16x32_bf16(aQl, b2, aq[st], 0, 0, 0);
                b1 = *(bf16x8*)&XKh[st*16+c][quad*8];
                b2 = *(bf16x8*)&XKl[st*16+c][quad*8];
                ak[st] = __builtin_amdgcn_mfma_f32_16x16x32_bf16(aKh, b1, ak[st], 0, 0, 0);
                ak[st] = __builtin_amdgcn_mfma_f32_16x16x32_bf16(aKh, b2, ak[st], 0, 0, 0);
                ak[st] = __builtin_amdgcn_mfma_f32_16x16x32_bf16(aKl, b1, ak[st], 0, 0, 0);
                ak[st] = __builtin_amdgcn_mfma_f32_16x16x32_bf16(aKl, b2, ak[st], 0, 0, 0);
                b1 = *(bf16x8*)&XVh[st*16+c][quad*8];
                av[st] = __builtin_amdgcn_mfma_f32_16x16x32_bf16(aVh, b1, av[st], 0, 0, 0);
                av[st] = __builtin_amdgcn_mfma_f32_16x16x32_bf16(aVl, b1, av[st], 0, 0, 0);
                b1 = *(bf16x8*)&XBh[st*16+c][quad*8];
                b2 = *(bf16x8*)&XBl[st*16+c][quad*8];
                ab[st] = __builtin_amdgcn_mfma_f32_16x16x32_bf16(aBh, b1, ab[st], 0, 0, 0);
                ab[st] = __builtin_amdgcn_mfma_f32_16x16x32_bf16(aBh, b2, ab[st], 0, 0, 0);
                ab[st] = __builtin_amdgcn_mfma_f32_16x16x32_bf16(aBl, b1, ab[st], 0, 0, 0);
                ab[st] = __builtin_amdgcn_mfma_f32_16x16x32_bf16(aBl, b2, ab[st], 0, 0, 0);
            }
        }
        __syncthreads();   // reads of cb done; writes to nb visible
    }
#undef XARR

    // ---- epilogue: RoPE * b in regs, then 2-pass LDS transpose -> coalesced stores ----
    float rq[2][4], rk[2][4];
    {
        int p0 = dt * 8 + 2 * quad;
        double inv0 = pow(10000.0, -(double)p0 / 32.0);
        double inv1 = pow(10000.0, -(double)(p0 + 1) / 32.0);
#pragma unroll
        for (int st = 0; st < 2; ++st) {
            int s = s0 + st * 16 + c;
            double a0 = (double)s * inv0, a1 = (double)s * inv1;
            float sn0 = (float)sin(a0), cs0 = (float)cos(a0);
            float sn1 = (float)sin(a1), cs1 = (float)cos(a1);
            rq[st][0] = (aq[st][0]*cs0 - aq[st][1]*sn0) * ab[st][0];
            rq[st][1] = (aq[st][0]*sn0 + aq[st][1]*cs0) * ab[st][1];
            rq[st][2] = (aq[st][2]*cs1 - aq[st][3]*sn1) * ab[st][2];
            rq[st][3] = (aq[st][2]*sn1 + aq[st][3]*cs1) * ab[st][3];
            rk[st][0] = (ak[st][0]*cs0 - ak[st][1]*sn0) * ab[st][0];
            rk[st][1] = (ak[st][0]*sn0 + ak[st][1]*cs0) * ab[st][1];
            rk[st][2] = (ak[st][2]*cs1 - ak[st][3]*sn1) * ab[st][2];
            rk[st][3] = (ak[st][2]*sn1 + ak[st][3]*cs1) * ab[st][3];
        }
    }
    // pass A: q hi/lo + v
    __syncthreads();   // all MFMA LDS reads done; safe to reuse pool
#pragma unroll
    for (int st = 0; st < 2; ++st) {
        unsigned short h0,l0,h1,l1,h2,l2,h3,l3;
        splitRN(rq[st][0],h0,l0); splitRN(rq[st][1],h1,l1);
        splitRN(rq[st][2],h2,l2); splitRN(rq[st][3],h3,l3);
        *(ushort4*)&T0[st*16+c][dt*16+4*quad] = make_ushort4(h0,h1,h2,h3);
        *(ushort4*)&T1[st*16+c][dt*16+4*quad] = make_ushort4(l0,l1,l2,l3);
#pragma unroll
        for (int reg = 0; reg < 4; ++reg)
            T2[dt * 16 + 4 * quad + reg][st * 16 + c] = bfbits(av[st][reg]);
    }
    __syncthreads();
    {
        int row = t >> 3, d8 = (t & 7) * 8;
        size_t qb = ((size_t)(h * S_LEN + s0 + row)) * 64 + d8;
        *(uint4*)&qhi[qb] = *(uint4*)&T0[row][d8];
        *(uint4*)&qlo[qb] = *(uint4*)&T1[row][d8];
        int d = t >> 2, s8 = (t & 3) * 8;
        size_t vb = ((size_t)(h * 64 + d)) * S_LEN + s0 + s8;
        *(uint4*)&vhi[vb] = *(uint4*)&T2[d][s8];
    }
    // pass B: k hi/lo
    __syncthreads();
#pragma unroll
    for (int st = 0; st < 2; ++st) {
        unsigned short h0,l0,h1,l1,h2,l2,h3,l3;
        splitRN(rk[st][0],h0,l0); splitRN(rk[st][1],h1,l1);
        splitRN(rk[st][2],h2,l2); splitRN(rk[st][3],h3,l3);
        *(ushort4*)&T0[st*16+c][dt*16+4*quad] = make_ushort4(h0,h1,h2,h3);
        *(ushort4*)&T1[st*16+c][dt*16+4*quad] = make_ushort4(l0,l1,l2,l3);
    }
    __syncthreads();
    {
        int row = t >> 3, d8 = (t & 7) * 8;
        size_t qb = ((size_t)(h * S_LEN + s0 + row)) * 64 + d8;
        *(uint4*)&khi[qb] = *(uint4*)&T0[row][d8];
        *(uint4*)&klo[qb] = *(uint4*)&T1[row][d8];
    }
}

// MFMA flash attention v3: QBLK=32, 128-thread blocks, grid 1024 -> 4 small
// independent blocks/CU (was 2 grid-pinned fat blocks). Single-buffered K/V,
// 2-barrier tile structure (staging isolated between barriers — the known-good
// r3 layout). LDS 36864 B. Math identical.
__global__ __launch_bounds__(128, 2)
void attn_mfma(const unsigned short* __restrict__ qh, const unsigned short* __restrict__ ql,
               const unsigned short* __restrict__ kh, const unsigned short* __restrict__ kl,
               const unsigned short* __restrict__ vh,
               const void* __restrict__ mask, float* __restrict__ out,
               const int* __restrict__ flags) {
    __shared__ unsigned short Kh[64][72], Kl[64][72];   // [key][d]
    __shared__ unsigned short Vt[64][72];               // [d][key]
    __shared__ unsigned short Sh[32][72], Sl[32][72];   // P: [q-row][key] (wave-private rows)
    const int menc = flags[0];
    const int t = threadIdx.x;
    // XCD-exclusive head swizzle (bijective: 1024 = 8 xcd * 2 h * 64 qt)
    const int lin = blockIdx.x;
    const int h = ((lin & 7) << 1) + ((lin >> 3) & 1);
    const int s0 = (lin >> 4) * 32;
    const int lane = t & 63, w = t >> 6, quad = lane >> 4, c = lane & 15;

    bf16x8 qfh[2], qfl[2];
#pragma unroll
    for (int ks = 0; ks < 2; ++ks) {
        size_t base = ((size_t)(h * S_LEN + s0 + 16 * w + c)) * 64 + ks * 32 + quad * 8;
        qfh[ks] = *(const bf16x8*)&qh[base];
        qfl[ks] = *(const bf16x8*)&ql[base];
    }
    int mq[4];
#pragma unroll
    for (int i = 0; i < 4; ++i) mq[i] = mask_at(mask, menc, s0 + 16 * w + quad * 4 + i);

    float m_i[4], l_i[4];
#pragma unroll
    for (int i = 0; i < 4; ++i) { m_i[i] = -INFINITY; l_i[i] = 0.0f; }
    f32x4 o_acc[4];
#pragma unroll
    for (int i = 0; i < 4; ++i) o_acc[i] = (f32x4){0.f,0.f,0.f,0.f};

    uint4 pre[12];
#pragma unroll
    for (int i = 0; i < 4; ++i) {
        int id = i * 128 + t, row = id >> 3, col8 = (id & 7) * 8;
        size_t kb = ((size_t)(h * S_LEN + row)) * 64 + col8;
        size_t vb = ((size_t)(h * 64 + row)) * S_LEN + col8;
        pre[0 + i] = *(const uint4*)&kh[kb];
        pre[4 + i] = *(const uint4*)&kl[kb];
        pre[8 + i] = *(const uint4*)&vh[vb];
    }

    for (int kt = 0; kt < 32; ++kt) {
        if (kt) __syncthreads();   // prev tile's K/V reads done
#pragma unroll
        for (int i = 0; i < 4; ++i) {
            int id = i * 128 + t, row = id >> 3, col8 = (id & 7) * 8;
            *(uint4*)&Kh[row][col8] = pre[0 + i];
            *(uint4*)&Kl[row][col8] = pre[4 + i];
            *(uint4*)&Vt[row][col8] = pre[8 + i];
        }
        __syncthreads();           // staged tile visible

        // issue next-tile global loads (hidden under this tile's compute)
        if (kt + 1 < 32) {
            const int kb0 = (kt + 1) * 64;
#pragma unroll
            for (int i = 0; i < 4; ++i) {
                int id = i * 128 + t, row = id >> 3, col8 = (id & 7) * 8;
                size_t kb = ((size_t)(h * S_LEN + kb0 + row)) * 64 + col8;
                size_t vb = ((size_t)(h * 64 + row)) * S_LEN + kb0 + col8;
                pre[0 + i] = *(const uint4*)&kh[kb];
                pre[4 + i] = *(const uint4*)&kl[kb];
                pre[8 + i] = *(const uint4*)&vh[vb];
            }
        }
        int mk[4];
#pragma unroll
        for (int nt = 0; nt < 4; ++nt) mk[nt] = mask_at(mask, menc, kt * 64 + 16 * nt + c);

        // ---- QK^T (3-MFMA split) ----
        f32x4 sc[4];
#pragma unroll
        for (int i = 0; i < 4; ++i) sc[i] = (f32x4){0.f,0.f,0.f,0.f};
#pragma unroll
        for (int nt = 0; nt < 4; ++nt)
#pragma unroll
            for (int ks = 0; ks < 2; ++ks) {
                bf16x8 kfh = *(bf16x8*)&Kh[nt * 16 + c][ks * 32 + quad * 8];
                bf16x8 kfl = *(bf16x8*)&Kl[nt * 16 + c][ks * 32 + quad * 8];
                sc[nt] = __builtin_amdgcn_mfma_f32_16x16x32_bf16(qfh[ks], kfh, sc[nt], 0, 0, 0);
                sc[nt] = __builtin_amdgcn_mfma_f32_16x16x32_bf16(qfh[ks], kfl, sc[nt], 0, 0, 0);
                sc[nt] = __builtin_amdgcn_mfma_f32_16x16x32_bf16(qfl[ks], kfh, sc[nt], 0, 0, 0);
            }

        float sm[4][4];
#pragma unroll
        for (int nt = 0; nt < 4; ++nt)
#pragma unroll
            for (int reg = 0; reg < 4; ++reg)
                sm[nt][reg] = (mq[reg] && mk[nt]) ? sc[nt][reg] * 0.125f : -1e30f;

        float rmax[4];
#pragma unroll
        for (int reg = 0; reg < 4; ++reg)
            rmax[reg] = fmaxf(fmaxf(sm[0][reg], sm[1][reg]), fmaxf(sm[2][reg], sm[3][reg]));
#pragma unroll
        for (int off = 1; off <= 8; off <<= 1)
#pragma unroll
            for (int reg = 0; reg < 4; ++reg)
                rmax[reg] = fmaxf(rmax[reg], __shfl_xor(rmax[reg], off, 64));

        float mn[4], alpha[4];
#pragma unroll
        for (int reg = 0; reg < 4; ++reg) {
            mn[reg] = fmaxf(m_i[reg], rmax[reg]);
            alpha[reg] = __expf(m_i[reg] - mn[reg]);
            m_i[reg] = mn[reg];
        }

        float rsum[4] = {0.f, 0.f, 0.f, 0.f};
#pragma unroll
        for (int nt = 0; nt < 4; ++nt)
#pragma unroll
            for (int reg = 0; reg < 4; ++reg) {
                float e = __expf(sm[nt][reg] - mn[reg]);
                rsum[reg] += e;
                unsigned short eh, el;
                splitRN(e, eh, el);
                Sh[16 * w + quad * 4 + reg][16 * nt + c] = eh;
                Sl[16 * w + quad * 4 + reg][16 * nt + c] = el;
            }
#pragma unroll
        for (int off = 1; off <= 8; off <<= 1)
#pragma unroll
            for (int reg = 0; reg < 4; ++reg)
                rsum[reg] += __shfl_xor(rsum[reg], off, 64);
#pragma unroll
        for (int reg = 0; reg < 4; ++reg) l_i[reg] = l_i[reg] * alpha[reg] + rsum[reg];
        // alpha-skip: multiplying by exactly 1.0 is a no-op -> skipping is bit-identical
        if (!__all(alpha[0] == 1.0f && alpha[1] == 1.0f &&
                   alpha[2] == 1.0f && alpha[3] == 1.0f)) {
#pragma unroll
            for (int nt = 0; nt < 4; ++nt)
#pragma unroll
                for (int reg = 0; reg < 4; ++reg) o_acc[nt][reg] *= alpha[reg];
        }

        // ---- PV (2-MFMA, V hi-only); S rows wave-private (lgkm-ordered) ----
#pragma unroll
        for (int ks = 0; ks < 2; ++ks) {
            bf16x8 pfh = *(bf16x8*)&Sh[16 * w + c][ks * 32 + quad * 8];
            bf16x8 pfl = *(bf16x8*)&Sl[16 * w + c][ks * 32 + quad * 8];
#pragma unroll
            for (int nt = 0; nt < 4; ++nt) {
                bf16x8 vf = *(bf16x8*)&Vt[nt * 16 + c][ks * 32 + quad * 8];
                o_acc[nt] = __builtin_amdgcn_mfma_f32_16x16x32_bf16(pfh, vf, o_acc[nt], 0, 0, 0);
                o_acc[nt] = __builtin_amdgcn_mfma_f32_16x16x32_bf16(pfl, vf, o_acc[nt], 0, 0, 0);
            }
        }
    }

#pragma unroll
    for (int reg = 0; reg < 4; ++reg) {
        float inv = 1.0f / l_i[reg];
        int row = s0 + 16 * w + quad * 4 + reg;
#pragma unroll
        for (int nt = 0; nt < 4; ++nt)
            out[(size_t)row * 1024 + h * 64 + nt * 16 + c] = o_acc[nt][reg] * inv;
    }
}

extern "C" void kernel_launch(void* const* d_in, const int* in_sizes, int n_in,
                              void* d_out, int out_size, void* d_ws, size_t ws_size,
                              hipStream_t stream) {
    const float* query = (const float*)d_in[0];
    const float* key   = (const float*)d_in[1];
    const float* value = (const float*)d_in[2];
    const float* b_emb = (const float*)d_in[3];
    const void*  mask  = d_in[4];
    const float* ll    = (const float*)d_in[5];
    const float* bproj = (const float*)d_in[6];
    float* out = (float*)d_out;

    const size_t HSD = (size_t)NHEAD * S_LEN * 64;     // 2M elements
    char* ws = (char*)d_ws;
    int* flags = (int*)ws;
    unsigned short* qhi = (unsigned short*)(ws + 4096);
    unsigned short* qlo = qhi + HSD;
    unsigned short* khi = qlo + HSD;
    unsigned short* klo = khi + HSD;
    unsigned short* vhi = klo + HSD;
    unsigned short* Wh  = vhi + HSD;                   // 4M elements
    unsigned short* Wl  = Wh + 4 * 1048576;            // 4M elements
    // total: 4 KB + 20 MB + 16 MB = ~36 MB

    detect_kernel<<<1, 64, 0, stream>>>(mask, flags);
    presplit_w<<<1024, 256, 0, stream>>>(ll, bproj, Wh, Wl);
    proj_fused6<<<1024, 256, 0, stream>>>(query, key, value, b_emb,
                                          Wh, Wl, qhi, qlo, khi, klo, vhi);
    attn_mfma<<<1024, 128, 0, stream>>>(qhi, qlo, khi, klo, vhi, mask, out, flags);
}

// Round 6
// 262.702 us; speedup vs baseline: 1.5593x; 1.5593x over previous
//
#include <hip/hip_runtime.h>
#include <hip/hip_bf16.h>
#include <math.h>

#define S_LEN 2048
#define NHEAD 16
#define DMODEL 1024

typedef short bf16x8 __attribute__((ext_vector_type(8)));
typedef float f32x4 __attribute__((ext_vector_type(4)));

static __device__ __forceinline__ unsigned short bfbits(float x) {
    __hip_bfloat16 h = __float2bfloat16(x);   // round-to-nearest
    unsigned short u; __builtin_memcpy(&u, &h, 2); return u;
}
static __device__ __forceinline__ float bf2f(unsigned short u) {
    union { unsigned int i; float f; } v; v.i = ((unsigned int)u) << 16; return v.f;
}
// round-to-nearest split: x ~= hi + lo, rel err ~2^-18
static __device__ __forceinline__ void splitRN(float x, unsigned short& hi, unsigned short& lo) {
    unsigned short h = bfbits(x);
    float r = x - bf2f(h);
    hi = h; lo = bfbits(r);
}
static __device__ __forceinline__ void split4(float4 x, ushort4& h4, ushort4& l4) {
    unsigned short h0,l0,h1,l1,h2,l2,h3,l3;
    splitRN(x.x,h0,l0); splitRN(x.y,h1,l1); splitRN(x.z,h2,l2); splitRN(x.w,h3,l3);
    h4 = make_ushort4(h0,h1,h2,h3); l4 = make_ushort4(l0,l1,l2,l3);
}

__device__ __forceinline__ int mask_at(const void* mp, int enc, int s) {
    if (enc) return ((const unsigned char*)mp)[s] != 0;
    return ((const unsigned int*)mp)[s] != 0u;
}

__global__ void detect_kernel(const void* __restrict__ mask, int* __restrict__ flags) {
    if (threadIdx.x == 0 && blockIdx.x == 0) {
        const unsigned int* m = (const unsigned int*)mask;
        int bytey = 0;
        for (int i = 0; i < 8; ++i) {
            unsigned int u = m[i];
            if (u != 0u && u != 1u && u != 0x3F800000u) bytey = 1;
        }
        flags[0] = bytey;
    }
}

// Pre-split + pre-layout W in MFMA-fragment order:
// Wh/Wl[stream][h][dt][kc][lane][8]; a wave's per-chunk fragment load is ONE
// coalesced 1 KB read.
__global__ __launch_bounds__(256)
void presplit_w(const float* __restrict__ ll, const float* __restrict__ bproj,
                unsigned short* __restrict__ Wh, unsigned short* __restrict__ Wl) {
    __shared__ unsigned short Th[64][72], Tl[64][72];   // [n][d_local]
    const int t = threadIdx.x;
    const int bid = blockIdx.x;
    const int stream = bid >> 8;
    const int rem = bid & 255;
    const int h = rem >> 4;
    const int d0 = (rem & 15) << 6;
    const float* src = (stream == 3) ? bproj : (ll + (size_t)stream * 1048576);
#pragma unroll
    for (int rep = 0; rep < 4; ++rep) {
        int fid = rep * 256 + t;
        int dl = fid >> 4, n4 = (fid & 15) * 4;
        float4 w = *(const float4*)&src[(size_t)(d0 + dl) * 1024 + h * 64 + n4];
        unsigned short hh, lo2;
#pragma unroll
        for (int m = 0; m < 4; ++m) { splitRN((&w.x)[m], hh, lo2); Th[n4+m][dl] = hh; Tl[n4+m][dl] = lo2; }
    }
    __syncthreads();
    size_t obase = (size_t)stream * 1048576;
#pragma unroll
    for (int rep = 0; rep < 2; ++rep) {
        int wid = rep * 256 + t;
        int n = wid >> 3, dl8 = (wid & 7) * 8;
        int dtile = n >> 4, cc = n & 15;
        int dglob = d0 + dl8;
        int kc = dglob >> 5;
        int qd = (dglob >> 3) & 3;
        size_t off = obase + (size_t)(h * 4 + dtile) * 16384 + (size_t)kc * 512
                   + (size_t)(qd * 16 + cc) * 8;
        *(uint4*)&Wh[off] = *(uint4*)&Th[n][dl8];
        *(uint4*)&Wl[off] = *(uint4*)&Tl[n][dl8];
    }
}

// Fused q/k/v/b_rotate projection v7: 3-MFMA split for q/k/b (lo x lo term
// dropped: ~2^-18 relative, negligible) -> 44 MFMA/chunk (was 56). Double-
// buffered X LDS, 1 barrier/chunk, 4 blocks/CU.
__global__ __launch_bounds__(256, 4)
void proj_fused7(const float* __restrict__ Xq, const float* __restrict__ Xk,
                 const float* __restrict__ Xv, const float* __restrict__ Xb,
                 const unsigned short* __restrict__ Wh, const unsigned short* __restrict__ Wl,
                 unsigned short* __restrict__ qhi, unsigned short* __restrict__ qlo,
                 unsigned short* __restrict__ khi, unsigned short* __restrict__ klo,
                 unsigned short* __restrict__ vhi) {
    __shared__ unsigned short smem[17920];   // 2 bufs x 7 arrays x [32][40] ushort
    unsigned short (*T0)[72] = (unsigned short(*)[72])(smem + 0);
    unsigned short (*T1)[72] = (unsigned short(*)[72])(smem + 2304);
    unsigned short (*T2)[40] = (unsigned short(*)[40])(smem + 4608);

    const int t = threadIdx.x;
    const int lin = blockIdx.x;
    const int xcd = lin & 7;
    const int inner = lin >> 3;          // 0..127
    const int h = inner >> 3;            // 0..15
    const int sg = inner & 7;            // 0..7
    const int s0 = (xcd * 8 + sg) * 32;
    const int lane = t & 63, dt = t >> 6, quad = lane >> 4, c = lane & 15;

    f32x4 aq[2], ak[2], av[2], ab[2];
#pragma unroll
    for (int i = 0; i < 2; ++i) {
        aq[i] = (f32x4){0.f,0.f,0.f,0.f}; ak[i] = (f32x4){0.f,0.f,0.f,0.f};
        av[i] = (f32x4){0.f,0.f,0.f,0.f}; ab[i] = (f32x4){0.f,0.f,0.f,0.f};
    }

    const int xr = t >> 3, xc = (t & 7) * 4;
    const size_t xg = (size_t)(s0 + xr) * DMODEL + xc;
    const size_t wb = (size_t)(h * 4 + dt) * 16384 + (size_t)lane * 8;

#define XARR(name, b, i) unsigned short (*name)[40] = (unsigned short(*)[40])(smem + (b) * 8960 + (i) * 1280)

    float4 pq, pk, pv, pb;
    pq = *(const float4*)&Xq[xg];
    pk = *(const float4*)&Xk[xg];
    pv = *(const float4*)&Xv[xg];
    pb = *(const float4*)&Xb[xg];
    {
        XARR(XQh,0,0); XARR(XQl,0,1); XARR(XKh,0,2); XARR(XKl,0,3);
        XARR(XVh,0,4); XARR(XBh,0,5); XARR(XBl,0,6);
        ushort4 h4, l4;
        split4(pq, h4, l4); *(ushort4*)&XQh[xr][xc] = h4; *(ushort4*)&XQl[xr][xc] = l4;
        split4(pk, h4, l4); *(ushort4*)&XKh[xr][xc] = h4; *(ushort4*)&XKl[xr][xc] = l4;
        split4(pb, h4, l4); *(ushort4*)&XBh[xr][xc] = h4; *(ushort4*)&XBl[xr][xc] = l4;
        *(ushort4*)&XVh[xr][xc] = make_ushort4(bfbits(pv.x),bfbits(pv.y),bfbits(pv.z),bfbits(pv.w));
    }
    pq = *(const float4*)&Xq[xg + 32];
    pk = *(const float4*)&Xk[xg + 32];
    pv = *(const float4*)&Xv[xg + 32];
    pb = *(const float4*)&Xb[xg + 32];
    __syncthreads();

    for (int kc = 0; kc < 32; ++kc) {
        const int cb = kc & 1, nb = cb ^ 1;
        size_t wo = wb + (size_t)kc * 512;
        bf16x8 aQh = *(const bf16x8*)&Wh[wo];
        bf16x8 aQl = *(const bf16x8*)&Wl[wo];
        bf16x8 aKh = *(const bf16x8*)&Wh[1048576 + wo];
        bf16x8 aKl = *(const bf16x8*)&Wl[1048576 + wo];
        bf16x8 aVh = *(const bf16x8*)&Wh[2097152 + wo];
        bf16x8 aVl = *(const bf16x8*)&Wl[2097152 + wo];
        bf16x8 aBh = *(const bf16x8*)&Wh[3145728 + wo];
        bf16x8 aBl = *(const bf16x8*)&Wl[3145728 + wo];

        if (kc + 1 < 32) {
            XARR(XQh,nb,0); XARR(XQl,nb,1); XARR(XKh,nb,2); XARR(XKl,nb,3);
            XARR(XVh,nb,4); XARR(XBh,nb,5); XARR(XBl,nb,6);
            ushort4 h4, l4;
            split4(pq, h4, l4); *(ushort4*)&XQh[xr][xc] = h4; *(ushort4*)&XQl[xr][xc] = l4;
            split4(pk, h4, l4); *(ushort4*)&XKh[xr][xc] = h4; *(ushort4*)&XKl[xr][xc] = l4;
            split4(pb, h4, l4); *(ushort4*)&XBh[xr][xc] = h4; *(ushort4*)&XBl[xr][xc] = l4;
            *(ushort4*)&XVh[xr][xc] = make_ushort4(bfbits(pv.x),bfbits(pv.y),bfbits(pv.z),bfbits(pv.w));
        }
        if (kc + 2 < 32) {
            size_t g = xg + (size_t)(kc + 2) * 32;
            pq = *(const float4*)&Xq[g];
            pk = *(const float4*)&Xk[g];
            pv = *(const float4*)&Xv[g];
            pb = *(const float4*)&Xb[g];
        }

        {
            XARR(XQh,cb,0); XARR(XQl,cb,1); XARR(XKh,cb,2); XARR(XKl,cb,3);
            XARR(XVh,cb,4); XARR(XBh,cb,5); XARR(XBl,cb,6);
#pragma unroll
            for (int st = 0; st < 2; ++st) {
                // 3-MFMA split: hi*hi + hi*lo + lo*hi (lo*lo dropped)
                bf16x8 b1 = *(bf16x8*)&XQh[st*16+c][quad*8];
                bf16x8 b2 = *(bf16x8*)&XQl[st*16+c][quad*8];
                aq[st] = __builtin_amdgcn_mfma_f32_16x16x32_bf16(aQh, b1, aq[st], 0, 0, 0);
                aq[st] = __builtin_amdgcn_mfma_f32_16x16x32_bf16(aQh, b2, aq[st], 0, 0, 0);
                aq[st] = __builtin_amdgcn_mfma_f32_16x16x32_bf16(aQl, b1, aq[st], 0, 0, 0);
                b1 = *(bf16x8*)&XKh[st*16+c][quad*8];
                b2 = *(bf16x8*)&XKl[st*16+c][quad*8];
                ak[st] = __builtin_amdgcn_mfma_f32_16x16x32_bf16(aKh, b1, ak[st], 0, 0, 0);
                ak[st] = __builtin_amdgcn_mfma_f32_16x16x32_bf16(aKh, b2, ak[st], 0, 0, 0);
                ak[st] = __builtin_amdgcn_mfma_f32_16x16x32_bf16(aKl, b1, ak[st], 0, 0, 0);
                b1 = *(bf16x8*)&XVh[st*16+c][quad*8];
                av[st] = __builtin_amdgcn_mfma_f32_16x16x32_bf16(aVh, b1, av[st], 0, 0, 0);
                av[st] = __builtin_amdgcn_mfma_f32_16x16x32_bf16(aVl, b1, av[st], 0, 0, 0);
                b1 = *(bf16x8*)&XBh[st*16+c][quad*8];
                b2 = *(bf16x8*)&XBl[st*16+c][quad*8];
                ab[st] = __builtin_amdgcn_mfma_f32_16x16x32_bf16(aBh, b1, ab[st], 0, 0, 0);
                ab[st] = __builtin_amdgcn_mfma_f32_16x16x32_bf16(aBh, b2, ab[st], 0, 0, 0);
                ab[st] = __builtin_amdgcn_mfma_f32_16x16x32_bf16(aBl, b1, ab[st], 0, 0, 0);
            }
        }
        __syncthreads();   // reads of cb done; writes to nb visible
    }
#undef XARR

    // ---- epilogue: RoPE * b in regs, then 2-pass LDS transpose -> coalesced stores ----
    // q gets the attention scale 1/sqrt(64)=0.125 folded in (power-of-2: bit-exact
    // through splitRN and MFMA; attn kernel no longer multiplies scores).
    float rq[2][4], rk[2][4];
    {
        int p0 = dt * 8 + 2 * quad;
        double inv0 = pow(10000.0, -(double)p0 / 32.0);
        double inv1 = pow(10000.0, -(double)(p0 + 1) / 32.0);
#pragma unroll
        for (int st = 0; st < 2; ++st) {
            int s = s0 + st * 16 + c;
            double a0 = (double)s * inv0, a1 = (double)s * inv1;
            float sn0 = (float)sin(a0), cs0 = (float)cos(a0);
            float sn1 = (float)sin(a1), cs1 = (float)cos(a1);
            rq[st][0] = (aq[st][0]*cs0 - aq[st][1]*sn0) * ab[st][0] * 0.125f;
            rq[st][1] = (aq[st][0]*sn0 + aq[st][1]*cs0) * ab[st][1] * 0.125f;
            rq[st][2] = (aq[st][2]*cs1 - aq[st][3]*sn1) * ab[st][2] * 0.125f;
            rq[st][3] = (aq[st][2]*sn1 + aq[st][3]*cs1) * ab[st][3] * 0.125f;
            rk[st][0] = (ak[st][0]*cs0 - ak[st][1]*sn0) * ab[st][0];
            rk[st][1] = (ak[st][0]*sn0 + ak[st][1]*cs0) * ab[st][1];
            rk[st][2] = (ak[st][2]*cs1 - ak[st][3]*sn1) * ab[st][2];
            rk[st][3] = (ak[st][2]*sn1 + ak[st][3]*cs1) * ab[st][3];
        }
    }
    // pass A: q hi/lo + v
    __syncthreads();   // all MFMA LDS reads done; safe to reuse pool
#pragma unroll
    for (int st = 0; st < 2; ++st) {
        unsigned short h0,l0,h1,l1,h2,l2,h3,l3;
        splitRN(rq[st][0],h0,l0); splitRN(rq[st][1],h1,l1);
        splitRN(rq[st][2],h2,l2); splitRN(rq[st][3],h3,l3);
        *(ushort4*)&T0[st*16+c][dt*16+4*quad] = make_ushort4(h0,h1,h2,h3);
        *(ushort4*)&T1[st*16+c][dt*16+4*quad] = make_ushort4(l0,l1,l2,l3);
#pragma unroll
        for (int reg = 0; reg < 4; ++reg)
            T2[dt * 16 + 4 * quad + reg][st * 16 + c] = bfbits(av[st][reg]);
    }
    __syncthreads();
    {
        int row = t >> 3, d8 = (t & 7) * 8;
        size_t qb = ((size_t)(h * S_LEN + s0 + row)) * 64 + d8;
        *(uint4*)&qhi[qb] = *(uint4*)&T0[row][d8];
        *(uint4*)&qlo[qb] = *(uint4*)&T1[row][d8];
        int d = t >> 2, s8 = (t & 3) * 8;
        size_t vb = ((size_t)(h * 64 + d)) * S_LEN + s0 + s8;
        *(uint4*)&vhi[vb] = *(uint4*)&T2[d][s8];
    }
    // pass B: k hi/lo
    __syncthreads();
#pragma unroll
    for (int st = 0; st < 2; ++st) {
        unsigned short h0,l0,h1,l1,h2,l2,h3,l3;
        splitRN(rk[st][0],h0,l0); splitRN(rk[st][1],h1,l1);
        splitRN(rk[st][2],h2,l2); splitRN(rk[st][3],h3,l3);
        *(ushort4*)&T0[st*16+c][dt*16+4*quad] = make_ushort4(h0,h1,h2,h3);
        *(ushort4*)&T1[st*16+c][dt*16+4*quad] = make_ushort4(l0,l1,l2,l3);
    }
    __syncthreads();
    {
        int row = t >> 3, d8 = (t & 7) * 8;
        size_t qb = ((size_t)(h * S_LEN + s0 + row)) * 64 + d8;
        *(uint4*)&khi[qb] = *(uint4*)&T0[row][d8];
        *(uint4*)&klo[qb] = *(uint4*)&T1[row][d8];
    }
}

// MFMA flash attention: r3-verbatim structure (known-good 109 us): 256 threads,
// double-buffered K/V LDS, 2 barriers/tile, staging between softmax and mid
// barrier, XCD-exclusive head swizzle. Only change: score scale folded into Q.
__global__ __launch_bounds__(256)
void attn_mfma(const unsigned short* __restrict__ qh, const unsigned short* __restrict__ ql,
               const unsigned short* __restrict__ kh, const unsigned short* __restrict__ kl,
               const unsigned short* __restrict__ vh,
               const void* __restrict__ mask, float* __restrict__ out,
               const int* __restrict__ flags) {
    __shared__ unsigned short Kh[2][64][72], Kl[2][64][72];   // [buf][key][d]
    __shared__ unsigned short Vt[2][64][72];                  // [buf][d][key]
    __shared__ unsigned short Sh[64][72], Sl[64][72];         // P: [q-row][key]
    const int menc = flags[0];
    const int t = threadIdx.x;
    // XCD-exclusive head swizzle (bijective: 512 = 8 xcd * 2 * 32 qt)
    const int lin = blockIdx.x + (blockIdx.y << 5);
    const int h = (lin & 7) * 2 + ((lin >> 3) & 1);
    const int s0 = (lin >> 4) * 64;
    const int lane = t & 63, w = t >> 6, quad = lane >> 4, c = lane & 15;

    bf16x8 qfh[2], qfl[2];
#pragma unroll
    for (int ks = 0; ks < 2; ++ks) {
        size_t base = ((size_t)(h * S_LEN + s0 + 16 * w + c)) * 64 + ks * 32 + quad * 8;
        qfh[ks] = *(const bf16x8*)&qh[base];
        qfl[ks] = *(const bf16x8*)&ql[base];
    }
    int mq[4];
#pragma unroll
    for (int i = 0; i < 4; ++i) mq[i] = mask_at(mask, menc, s0 + 16 * w + quad * 4 + i);

    float m_i[4], l_i[4];
#pragma unroll
    for (int i = 0; i < 4; ++i) { m_i[i] = -INFINITY; l_i[i] = 0.0f; }
    f32x4 o_acc[4];
#pragma unroll
    for (int i = 0; i < 4; ++i) o_acc[i] = (f32x4){0.f,0.f,0.f,0.f};

    uint4 pre[6];
#pragma unroll
    for (int i = 0; i < 2; ++i) {
        int id = i * 256 + t, row = id >> 3, col8 = (id & 7) * 8;
        size_t kb = ((size_t)(h * S_LEN + row)) * 64 + col8;
        size_t vb = ((size_t)(h * 64 + row)) * S_LEN + col8;
        pre[0 + i] = *(const uint4*)&kh[kb];
        pre[2 + i] = *(const uint4*)&kl[kb];
        pre[4 + i] = *(const uint4*)&vh[vb];
    }
#pragma unroll
    for (int i = 0; i < 2; ++i) {
        int id = i * 256 + t, row = id >> 3, col8 = (id & 7) * 8;
        *(uint4*)&Kh[0][row][col8] = pre[0 + i];
        *(uint4*)&Kl[0][row][col8] = pre[2 + i];
        *(uint4*)&Vt[0][row][col8] = pre[4 + i];
    }
    __syncthreads();

    int cur = 0;
    for (int kt = 0; kt < 32; ++kt) {
        // issue next-tile global loads first (hidden under QK + softmax)
        if (kt + 1 < 32) {
            const int kb0 = (kt + 1) * 64;
#pragma unroll
            for (int i = 0; i < 2; ++i) {
                int id = i * 256 + t, row = id >> 3, col8 = (id & 7) * 8;
                size_t kb = ((size_t)(h * S_LEN + kb0 + row)) * 64 + col8;
                size_t vb = ((size_t)(h * 64 + row)) * S_LEN + kb0 + col8;
                pre[0 + i] = *(const uint4*)&kh[kb];
                pre[2 + i] = *(const uint4*)&kl[kb];
                pre[4 + i] = *(const uint4*)&vh[vb];
            }
        }
        int mk[4];
#pragma unroll
        for (int nt = 0; nt < 4; ++nt) mk[nt] = mask_at(mask, menc, kt * 64 + 16 * nt + c);

        // ---- QK^T (3-MFMA split) ----
        f32x4 sc[4];
#pragma unroll
        for (int i = 0; i < 4; ++i) sc[i] = (f32x4){0.f,0.f,0.f,0.f};
#pragma unroll
        for (int nt = 0; nt < 4; ++nt)
#pragma unroll
            for (int ks = 0; ks < 2; ++ks) {
                bf16x8 kfh = *(bf16x8*)&Kh[cur][nt * 16 + c][ks * 32 + quad * 8];
                bf16x8 kfl = *(bf16x8*)&Kl[cur][nt * 16 + c][ks * 32 + quad * 8];
                sc[nt] = __builtin_amdgcn_mfma_f32_16x16x32_bf16(qfh[ks], kfh, sc[nt], 0, 0, 0);
                sc[nt] = __builtin_amdgcn_mfma_f32_16x16x32_bf16(qfh[ks], kfl, sc[nt], 0, 0, 0);
                sc[nt] = __builtin_amdgcn_mfma_f32_16x16x32_bf16(qfl[ks], kfh, sc[nt], 0, 0, 0);
            }

        float sm[4][4];
#pragma unroll
        for (int nt = 0; nt < 4; ++nt)
#pragma unroll
            for (int reg = 0; reg < 4; ++reg)
                sm[nt][reg] = (mq[reg] && mk[nt]) ? sc[nt][reg] : -1e30f;   // scale pre-folded into Q

        float rmax[4];
#pragma unroll
        for (int reg = 0; reg < 4; ++reg)
            rmax[reg] = fmaxf(fmaxf(sm[0][reg], sm[1][reg]), fmaxf(sm[2][reg], sm[3][reg]));
#pragma unroll
        for (int off = 1; off <= 8; off <<= 1)
#pragma unroll
            for (int reg = 0; reg < 4; ++reg)
                rmax[reg] = fmaxf(rmax[reg], __shfl_xor(rmax[reg], off, 64));

        float mn[4], alpha[4];
#pragma unroll
        for (int reg = 0; reg < 4; ++reg) {
            mn[reg] = fmaxf(m_i[reg], rmax[reg]);
            alpha[reg] = __expf(m_i[reg] - mn[reg]);
            m_i[reg] = mn[reg];
        }

        float rsum[4] = {0.f, 0.f, 0.f, 0.f};
#pragma unroll
        for (int nt = 0; nt < 4; ++nt)
#pragma unroll
            for (int reg = 0; reg < 4; ++reg) {
                float e = __expf(sm[nt][reg] - mn[reg]);
                rsum[reg] += e;
                unsigned short eh, el;
                splitRN(e, eh, el);
                Sh[16 * w + quad * 4 + reg][16 * nt + c] = eh;
                Sl[16 * w + quad * 4 + reg][16 * nt + c] = el;
            }
#pragma unroll
        for (int off = 1; off <= 8; off <<= 1)
#pragma unroll
            for (int reg = 0; reg < 4; ++reg)
                rsum[reg] += __shfl_xor(rsum[reg], off, 64);
#pragma unroll
        for (int reg = 0; reg < 4; ++reg) l_i[reg] = l_i[reg] * alpha[reg] + rsum[reg];
#pragma unroll
        for (int nt = 0; nt < 4; ++nt)
#pragma unroll
            for (int reg = 0; reg < 4; ++reg) o_acc[nt][reg] *= alpha[reg];

        // stage next tile into the other buffer (pre-loads have had QK+softmax to land)
        if (kt + 1 < 32) {
            const int nxt = cur ^ 1;
#pragma unroll
            for (int i = 0; i < 2; ++i) {
                int id = i * 256 + t, row = id >> 3, col8 = (id & 7) * 8;
                *(uint4*)&Kh[nxt][row][col8] = pre[0 + i];
                *(uint4*)&Kl[nxt][row][col8] = pre[2 + i];
                *(uint4*)&Vt[nxt][row][col8] = pre[4 + i];
            }
        }
        __syncthreads();   // P visible; next K/V visible for next iter

        // ---- PV (2-MFMA, V hi-only) ----
#pragma unroll
        for (int ks = 0; ks < 2; ++ks) {
            bf16x8 pfh = *(bf16x8*)&Sh[16 * w + c][ks * 32 + quad * 8];
            bf16x8 pfl = *(bf16x8*)&Sl[16 * w + c][ks * 32 + quad * 8];
#pragma unroll
            for (int nt = 0; nt < 4; ++nt) {
                bf16x8 vf = *(bf16x8*)&Vt[cur][nt * 16 + c][ks * 32 + quad * 8];
                o_acc[nt] = __builtin_amdgcn_mfma_f32_16x16x32_bf16(pfh, vf, o_acc[nt], 0, 0, 0);
                o_acc[nt] = __builtin_amdgcn_mfma_f32_16x16x32_bf16(pfl, vf, o_acc[nt], 0, 0, 0);
            }
        }
        __syncthreads();   // PV done: S reusable, old buffer free
        cur ^= 1;
    }

#pragma unroll
    for (int reg = 0; reg < 4; ++reg) {
        float inv = 1.0f / l_i[reg];
        int row = s0 + 16 * w + quad * 4 + reg;
#pragma unroll
        for (int nt = 0; nt < 4; ++nt)
            out[(size_t)row * 1024 + h * 64 + nt * 16 + c] = o_acc[nt][reg] * inv;
    }
}

extern "C" void kernel_launch(void* const* d_in, const int* in_sizes, int n_in,
                              void* d_out, int out_size, void* d_ws, size_t ws_size,
                              hipStream_t stream) {
    const float* query = (const float*)d_in[0];
    const float* key   = (const float*)d_in[1];
    const float* value = (const float*)d_in[2];
    const float* b_emb = (const float*)d_in[3];
    const void*  mask  = d_in[4];
    const float* ll    = (const float*)d_in[5];
    const float* bproj = (const float*)d_in[6];
    float* out = (float*)d_out;

    const size_t HSD = (size_t)NHEAD * S_LEN * 64;     // 2M elements
    char* ws = (char*)d_ws;
    int* flags = (int*)ws;
    unsigned short* qhi = (unsigned short*)(ws + 4096);
    unsigned short* qlo = qhi + HSD;
    unsigned short* khi = qlo + HSD;
    unsigned short* klo = khi + HSD;
    unsigned short* vhi = klo + HSD;
    unsigned short* Wh  = vhi + HSD;                   // 4M elements
    unsigned short* Wl  = Wh + 4 * 1048576;            // 4M elements
    // total: 4 KB + 20 MB + 16 MB = ~36 MB

    detect_kernel<<<1, 64, 0, stream>>>(mask, flags);
    presplit_w<<<1024, 256, 0, stream>>>(ll, bproj, Wh, Wl);
    proj_fused7<<<1024, 256, 0, stream>>>(query, key, value, b_emb,
                                          Wh, Wl, qhi, qlo, khi, klo, vhi);
    attn_mfma<<<dim3(32, 16), 256, 0, stream>>>(qhi, qlo, khi, klo, vhi, mask, out, flags);
}